// Round 6
// baseline (290.496 us; speedup 1.0000x reference)
//
#include <hip/hip_runtime.h>
#include <math.h>

// Problem constants (B=4, N=2048, C=81)
#define NPROP 2048
#define NIMG 4
#define NCLS 81
#define REGW 648          // C*8
#define SCORE_THRESH 0.05f
#define NMS_T 0.5f
#define DETS 100
#define XC 1023.0f        // IMG_W - 1
#define YC 799.0f         // IMG_H - 1
#define BBOX_CLIP 4.135166556742356f  // log(1000/16)
#define MAXC 640          // LDS box-cache capacity (sorted positions)

// ---------------------------------------------------------------------------
// K1: per-row softmax-argmax -> v32 (flipped score bits, 0xFFFFFFFF=invalid)
// and ci16 (argmax class). One wave per row, 4 rows/block, 2048 blocks:
// logits read at full-chip HBM parallelism (the R5 lesson: ~10 B/cyc/CU).
// ---------------------------------------------------------------------------
__global__ __launch_bounds__(256) void score_kernel(
    const float* __restrict__ logits,
    unsigned* __restrict__ v32G, unsigned short* __restrict__ ci16G) {
  int row  = blockIdx.x * 4 + (threadIdx.x >> 6);
  int lane = threadIdx.x & 63;
  const float* lr = logits + (size_t)row * NCLS;
  float a = lr[lane];
  float b = (lane < NCLS - 64) ? lr[lane + 64] : -INFINITY;
  float v; int ci;
  if (b > a) { v = b; ci = lane + 64; } else { v = a; ci = lane; }
  for (int o = 32; o; o >>= 1) {        // wave argmax, min-index ties
    float ov = __shfl_xor(v, o);
    int   oc = __shfl_xor(ci, o);
    if (ov > v || (ov == v && oc < ci)) { v = ov; ci = oc; }
  }
  float e = expf(a - v) + ((lane < NCLS - 64) ? expf(b - v) : 0.0f);
  for (int o = 32; o; o >>= 1) e += __shfl_xor(e, o);
  if (lane == 0) {
    float score = 1.0f / e;             // softmax at argmax (numerator exp(0))
    unsigned vv = 0xFFFFFFFFu;
    if (ci >= 1 && score > SCORE_THRESH) {
      unsigned uu = __float_as_uint(score);
      uu = (uu & 0x80000000u) ? ~uu : (uu | 0x80000000u);
      vv = ~uu;                         // ascending vv == descending score
    }
    v32G[row]  = vv;
    ci16G[row] = (unsigned short)ci;
  }
}

// ---------------------------------------------------------------------------
// K2: per image (4 blocks, 1024 threads): compact ALL valid rows, rank-sort
// (one LDS-broadcast pass, 1 barrier), decode top<=MAXC boxes to LDS, dual
// chunked greedy NMS with early stop at 100 AND-survivors, direct output.
// No histogram/threshold/tranche machinery — complete order, structurally
// exact early stop.
// ---------------------------------------------------------------------------
struct SN {
  unsigned long long keys[NPROP];        // 16 KB  (v32<<16)|row, valid only
  unsigned short sidx[NPROP];            // 4 KB   sorted position -> row
  unsigned v32s[NPROP];                  // 8 KB   v32 per row
  float4 bxL[MAXC], bxR[MAXC];           // 20 KB  decoded boxes (sorted pos)
  float  arL[MAXC], arR[MAXC];           // 5 KB
  unsigned long long keepbL[NPROP / 64]; // 256 B
  unsigned long long keepbR[NPROP / 64]; // 256 B
  unsigned long long rowmL[64], rowmR[64];  // 1 KB  64x64 chunk bit matrices
  float4 cbL[64], cbR[64];               // 2 KB   chunk survivor boxes
  float  cbLa[64], cbRa[64];             // 512 B
  unsigned long long aL, aR;
  int cnt, prevCount, done, ccL, ccR;
  unsigned kthV;
};                                        // ~57.6 KB

__device__ __forceinline__ float areaf(float4 v) {
  return fmaxf(v.z - v.x + 1.0f, 0.0f) * fmaxf(v.w - v.y + 1.0f, 0.0f);
}
__device__ __forceinline__ bool iou_gt(float4 a, float aa, float4 b, float ba) {
  float ix1 = fmaxf(a.x, b.x), iy1 = fmaxf(a.y, b.y);
  float ix2 = fminf(a.z, b.z), iy2 = fminf(a.w, b.w);
  float iw = fmaxf(ix2 - ix1 + 1.0f, 0.0f);
  float ih = fmaxf(iy2 - iy1 + 1.0f, 0.0f);
  float inter = iw * ih;
  return inter > NMS_T * fmaxf(aa + ba - inter, 1e-6f);
}
__device__ __forceinline__ float score_from_v(unsigned v) {
  unsigned uu = ~v;
  unsigned bits = (uu & 0x80000000u) ? (uu & 0x7fffffffu) : ~uu;
  return __uint_as_float(bits);
}
// maskrcnn BoxCoder.decode + clip for one side (isR: right regression slots)
__device__ __forceinline__ float4 decode_side(const float* __restrict__ reg,
                                              const float4* __restrict__ props,
                                              int grow, int ci, int isR) {
  const float* r = reg + (size_t)grow * REGW + ci * 8 + isR * 4;
  float4 P = props[grow];
  float w  = P.z - P.x + 1.0f;
  float h  = P.w - P.y + 1.0f;
  float cx = P.x + 0.5f * w;
  float cy = P.y + 0.5f * h;
  float dx = r[0] / 10.0f;
  float dy = r[1] / 10.0f;
  float dw = fminf(r[2] / 5.0f, BBOX_CLIP);
  float dh = fminf(r[3] / 5.0f, BBOX_CLIP);
  float pcx = dx * w + cx;
  float pcy = dy * h + cy;
  float pw = expf(dw) * w;
  float ph = expf(dh) * h;
  float4 o;
  o.x = fminf(fmaxf(pcx - 0.5f * pw, 0.0f), XC);
  o.y = fminf(fmaxf(pcy - 0.5f * ph, 0.0f), YC);
  o.z = fminf(fmaxf(pcx + 0.5f * pw - 1.0f, 0.0f), XC);
  o.w = fminf(fmaxf(pcy + 0.5f * ph - 1.0f, 0.0f), YC);
  return o;
}
// box at sorted position pos; LDS cache for pos<MAXC, global decode beyond
__device__ __forceinline__ float4 get_sbox(SN* S, const float* reg,
                                           const float4* lp4, const float4* rp4,
                                           const unsigned short* ci16G,
                                           int b, int pos, int isR) {
  if (pos < MAXC) return isR ? S->bxR[pos] : S->bxL[pos];
  int row = S->sidx[pos];
  int grow = b * NPROP + row;
  return decode_side(reg, isR ? rp4 : lp4, grow, ci16G[grow], isR);
}

__global__ __launch_bounds__(1024) void nms_kernel(
    const float* __restrict__ reg, const float* __restrict__ lp,
    const float* __restrict__ rp, const unsigned* __restrict__ v32G,
    const unsigned short* __restrict__ ci16G, float* __restrict__ out) {
  __shared__ SN S;
  int b = blockIdx.x, tid = threadIdx.x, ln = tid & 63, w = tid >> 6;
  const float4* lp4 = (const float4*)lp;
  const float4* rp4 = (const float4*)rp;
  float* ob = out + (size_t)b * NPROP * 9;

  // zero this image's output
  float4* ob4 = (float4*)ob;
  float4 z4 = make_float4(0.f, 0.f, 0.f, 0.f);
  for (int i = tid; i < NPROP * 9 / 4; i += 1024) ob4[i] = z4;

  if (tid == 0) { S.cnt = 0; S.prevCount = 0; S.done = 0; S.kthV = 0u; }
  __syncthreads();

  // ---- compact valid rows into keys (wave-aggregated) ----
  for (int p = tid; p < NPROP; p += 1024) {
    unsigned v = v32G[b * NPROP + p];
    S.v32s[p] = v;
    bool cand = (v != 0xFFFFFFFFu);
    unsigned long long mb = __ballot(cand);
    int lpos = (int)__popcll(mb & ((1ull << ln) - 1ull));
    int wb = 0;
    if (ln == 0 && mb) wb = atomicAdd(&S.cnt, (int)__popcll(mb));
    wb = __shfl(wb, 0);
    if (cand) S.keys[wb + lpos] = ((unsigned long long)v << 16) | (unsigned)p;
  }
  __syncthreads();
  int C2 = S.cnt;                        // number of valid candidates
  int CbEnd = (C2 + 63) & ~63;

  // ---- rank-sort: each thread ranks <=2 keys in ONE broadcast pass ----
  {
    int i0 = tid, i1 = tid + 1024;
    unsigned long long k0 = (i0 < C2) ? S.keys[i0] : ~0ull;
    unsigned long long k1 = (i1 < C2) ? S.keys[i1] : ~0ull;
    int r0 = 0, r1 = 0;
#pragma unroll 4
    for (int j = 0; j < C2; ++j) {
      unsigned long long kj = S.keys[j];   // same j all threads -> broadcast
      r0 += (kj < k0) ? 1 : 0;
      r1 += (kj < k1) ? 1 : 0;
    }
    if (i0 < C2) S.sidx[r0] = (unsigned short)(k0 & 0xFFFFull);
    if (i1 < C2) S.sidx[r1] = (unsigned short)(k1 & 0xFFFFull);
  }
  // pads (keys unique -> ranks are a permutation of [0,C2))
  for (int i = C2 + tid; i < CbEnd; i += 1024) S.sidx[i] = 0;
  // init keep bitmask words
  for (int wd = tid; wd < NPROP / 64; wd += 1024) {
    int b0 = wd << 6;
    unsigned long long mf = 0ull;
    if (C2 >= b0 + 64) mf = ~0ull;
    else if (C2 > b0)  mf = (1ull << (C2 - b0)) - 1ull;
    S.keepbL[wd] = mf; S.keepbR[wd] = mf;
  }
  __syncthreads();

  // ---- decode boxes for sorted positions < min(CbEnd, MAXC) into LDS ----
  {
    int lim = min(CbEnd, MAXC);
    for (int i = tid; i < lim; i += 1024) {
      if (i < C2) {
        int row = S.sidx[i];
        int grow = b * NPROP + row;
        int ci = ci16G[grow];
        float4 L = decode_side(reg, lp4, grow, ci, 0);
        float4 R = decode_side(reg, rp4, grow, ci, 1);
        S.bxL[i] = L; S.arL[i] = areaf(L);
        S.bxR[i] = R; S.arR[i] = areaf(R);
      } else {
        S.bxL[i] = z4; S.arL[i] = 1.0f;
        S.bxR[i] = z4; S.arR[i] = 1.0f;
      }
    }
  }
  __syncthreads();

  // ---- chunked dual greedy NMS, early stop at 100 AND-survivors ----
  for (int base = 0; base < CbEnd; base += 64) {
    // ph1: 64x64 IoU bit matrices; waves 0-7 build L, 8-15 build R
    {
      int isR = (w >= 8);
      float4 cbx = get_sbox(&S, reg, lp4, rp4, ci16G, b, base + ln, isR);
      float car = (base + ln < MAXC) ? (isR ? S.arR[base + ln] : S.arL[base + ln])
                                     : areaf(cbx);
      int w8 = w & 7;
#pragma unroll
      for (int k = 0; k < 8; ++k) {
        int row = w8 * 8 + k;
        float4 rbx;
        rbx.x = __shfl(cbx.x, row); rbx.y = __shfl(cbx.y, row);
        rbx.z = __shfl(cbx.z, row); rbx.w = __shfl(cbx.w, row);
        float rar = __shfl(car, row);
        bool bit = (ln > row) && iou_gt(rbx, rar, cbx, car);
        unsigned long long bal = __ballot(bit);
        if (ln == 0) { if (isR) S.rowmR[row] = bal; else S.rowmL[row] = bal; }
      }
    }
    __syncthreads();
    // ph2: branchless serial greedy per side (waves 0=L, 1=R)
    if (tid < 128) {
      int isR = (tid >= 64);
      unsigned long long* km = isR ? S.keepbR : S.keepbL;
      unsigned long long* rm = isR ? S.rowmR  : S.rowmL;
      unsigned long long a = km[base >> 6];
#pragma unroll
      for (int j = 0; j < 64; ++j)
        a &= ~((0ull - ((a >> j) & 1ull)) & rm[j]);
      if (ln == 0) {
        km[base >> 6] = a;
        if (isR) { S.aR = a; S.ccR = __popcll(a); }
        else     { S.aL = a; S.ccL = __popcll(a); }
      }
      if ((a >> ln) & 1ull) {            // compact survivors for ph3
        int pos = __popcll(a & ((1ull << ln) - 1ull));
        float4 v = get_sbox(&S, reg, lp4, rp4, ci16G, b, base + ln, isR);
        if (isR) { S.cbR[pos] = v; S.cbRa[pos] = areaf(v); }
        else     { S.cbL[pos] = v; S.cbLa[pos] = areaf(v); }
      }
    }
    __syncthreads();
    // ph2b (wave 0): AND-survivors -> rank, kth, output, stop check
    if (w == 0) {
      unsigned long long m = S.aL & S.aR;
      int before = S.prevCount;
      bool bit = (m >> ln) & 1ull;
      int rank = before + (int)__popcll(m & ((1ull << ln) - 1ull));
      int row = S.sidx[base + ln];
      unsigned vA = S.v32s[row];
      unsigned long long selm = __ballot(bit && rank == DETS - 1);
      unsigned keffV = S.kthV;
      if (selm) keffV = __shfl(vA, __ffsll(selm) - 1);
      bool qual = bit && (rank < DETS || vA == keffV);  // top-100 or tie at kth
      if (qual) {
        float4 L = get_sbox(&S, reg, lp4, rp4, ci16G, b, base + ln, 0);
        float4 R = get_sbox(&S, reg, lp4, rp4, ci16G, b, base + ln, 1);
        float s = score_from_v(vA);
        float* orow = ob + row * 9;
        orow[0]=L.x; orow[1]=L.y; orow[2]=L.z; orow[3]=L.w;
        orow[4]=R.x; orow[5]=R.y; orow[6]=R.z; orow[7]=R.w;
        orow[8]=s;
      }
      if (ln == 0) {
        if (selm) S.kthV = keffV;
        int nc = before + (int)__popcll(m);
        S.prevCount = nc;
        if (nc >= DETS) {               // stop unless exact score-tie continues
          int nxt = base + 64;
          bool cont = false;
          if (nxt < C2) cont = (S.v32s[S.sidx[nxt]] == keffV);
          if (!cont) S.done = 1;
        }
      }
    } else {
      // ph3 (waves 1-15): chunk survivors suppress later positions
      int cL = S.ccL, cR = S.ccR;
      if ((cL | cR) != 0) {
        for (int p = base + 64 + (tid - 64); p < CbEnd; p += 960) {
          float4 mbL = get_sbox(&S, reg, lp4, rp4, ci16G, b, p, 0);
          float al = (p < MAXC) ? S.arL[p] : areaf(mbL);
          bool supL = false;
          for (int q = 0; q < cL; ++q)
            supL = supL || iou_gt(mbL, al, S.cbL[q], S.cbLa[q]);
          if (supL) atomicAnd(&S.keepbL[p >> 6], ~(1ull << (p & 63)));
          float4 mbR = get_sbox(&S, reg, lp4, rp4, ci16G, b, p, 1);
          float ar_ = (p < MAXC) ? S.arR[p] : areaf(mbR);
          bool supR = false;
          for (int q = 0; q < cR; ++q)
            supR = supR || iou_gt(mbR, ar_, S.cbR[q], S.cbRa[q]);
          if (supR) atomicAnd(&S.keepbR[p >> 6], ~(1ull << (p & 63)));
        }
      }
    }
    __syncthreads();
    if (S.done) break;
  }
}

// ---------------------------------------------------------------------------
extern "C" void kernel_launch(void* const* d_in, const int* in_sizes, int n_in,
                              void* d_out, int out_size, void* d_ws, size_t ws_size,
                              hipStream_t stream) {
  const float* logits = (const float*)d_in[0];   // [8192, 81]
  const float* reg    = (const float*)d_in[1];   // [8192, 648]
  const float* lprop  = (const float*)d_in[2];   // [8192, 4]
  const float* rprop  = (const float*)d_in[3];   // [8192, 4]
  float* out = (float*)d_out;                    // [4, 2048, 9]

  unsigned*       v32G  = (unsigned*)d_ws;            // 8192 u32 (32 KB)
  unsigned short* ci16G = (unsigned short*)(v32G + NIMG * NPROP);  // 8192 u16

  score_kernel<<<NIMG * NPROP / 4, 256,  0, stream>>>(logits, v32G, ci16G);
  nms_kernel  <<<NIMG,             1024, 0, stream>>>(reg, lprop, rprop,
                                                      v32G, ci16G, out);
}

// Round 7
// 148.957 us; speedup vs baseline: 1.9502x; 1.9502x over previous
//
#include <hip/hip_runtime.h>
#include <math.h>

// Problem constants (B=4, N=2048, C=81)
#define NPROP 2048
#define NIMG 4
#define NCLS 81
#define REGW 648          // C*8
#define SCORE_THRESH 0.05f
#define NMS_T 0.5f
#define DETS 100
#define XC 1023.0f        // IMG_W - 1
#define YC 799.0f         // IMG_H - 1
#define BBOX_CLIP 4.135166556742356f  // log(1000/16)
#define NBIN 4096         // 12-bit score-bin histogram
#define SEL 320           // tranche-1 target size
#define MAXC 640          // fast-path candidate cap

__device__ __forceinline__ float areaf(float4 v) {
  return fmaxf(v.z - v.x + 1.0f, 0.0f) * fmaxf(v.w - v.y + 1.0f, 0.0f);
}
__device__ __forceinline__ bool iou_gt(float4 a, float aa, float4 b, float ba) {
  float ix1 = fmaxf(a.x, b.x), iy1 = fmaxf(a.y, b.y);
  float ix2 = fminf(a.z, b.z), iy2 = fminf(a.w, b.w);
  float iw = fmaxf(ix2 - ix1 + 1.0f, 0.0f);
  float ih = fmaxf(iy2 - iy1 + 1.0f, 0.0f);
  float inter = iw * ih;
  return inter > NMS_T * fmaxf(aa + ba - inter, 1e-6f);
}
__device__ __forceinline__ float score_from_v(unsigned v) {
  unsigned uu = ~v;
  unsigned bits = (uu & 0x80000000u) ? (uu & 0x7fffffffu) : ~uu;
  return __uint_as_float(bits);
}
__device__ __forceinline__ float4 decode_side(const float* __restrict__ reg,
                                              const float4* __restrict__ props,
                                              int grow, int ci, int isR) {
  const float* r = reg + (size_t)grow * REGW + ci * 8 + isR * 4;
  float4 P = props[grow];
  float w  = P.z - P.x + 1.0f;
  float h  = P.w - P.y + 1.0f;
  float cx = P.x + 0.5f * w;
  float cy = P.y + 0.5f * h;
  float dx = r[0] / 10.0f;
  float dy = r[1] / 10.0f;
  float dw = fminf(r[2] / 5.0f, BBOX_CLIP);
  float dh = fminf(r[3] / 5.0f, BBOX_CLIP);
  float pcx = dx * w + cx;
  float pcy = dy * h + cy;
  float pw = expf(dw) * w;
  float ph = expf(dh) * h;
  float4 o;
  o.x = fminf(fmaxf(pcx - 0.5f * pw, 0.0f), XC);
  o.y = fminf(fmaxf(pcy - 0.5f * ph, 0.0f), YC);
  o.z = fminf(fmaxf(pcx + 0.5f * pw - 1.0f, 0.0f), XC);
  o.w = fminf(fmaxf(pcy + 0.5f * ph - 1.0f, 0.0f), YC);
  return o;
}

// ---------------------------------------------------------------------------
// K1: wide per-row softmax-argmax -> v32 (flipped score bits) + ci16.
// ---------------------------------------------------------------------------
__global__ __launch_bounds__(256) void score_kernel(
    const float* __restrict__ logits,
    unsigned* __restrict__ v32G, unsigned short* __restrict__ ci16G) {
  int row  = blockIdx.x * 4 + (threadIdx.x >> 6);
  int lane = threadIdx.x & 63;
  const float* lr = logits + (size_t)row * NCLS;
  float a = lr[lane];
  float b = (lane < NCLS - 64) ? lr[lane + 64] : -INFINITY;
  float v; int ci;
  if (b > a) { v = b; ci = lane + 64; } else { v = a; ci = lane; }
  for (int o = 32; o; o >>= 1) {
    float ov = __shfl_xor(v, o);
    int   oc = __shfl_xor(ci, o);
    if (ov > v || (ov == v && oc < ci)) { v = ov; ci = oc; }
  }
  float e = expf(a - v) + ((lane < NCLS - 64) ? expf(b - v) : 0.0f);
  for (int o = 32; o; o >>= 1) e += __shfl_xor(e, o);
  if (lane == 0) {
    float score = 1.0f / e;
    unsigned vv = 0xFFFFFFFFu;
    if (ci >= 1 && score > SCORE_THRESH) {
      unsigned uu = __float_as_uint(score);
      uu = (uu & 0x80000000u) ? ~uu : (uu | 0x80000000u);
      vv = ~uu;
    }
    v32G[row]  = vv;
    ci16G[row] = (unsigned short)ci;
  }
}

// ---------------------------------------------------------------------------
// K2: per image: histogram threshold (SEL), compact tranche-1, rank-sort it
// with ONLY the owning waves (~6) issuing the LDS broadcast loop.
// ---------------------------------------------------------------------------
__global__ __launch_bounds__(1024) void select_kernel(
    const unsigned* __restrict__ v32G,
    unsigned short* __restrict__ srowG, unsigned* __restrict__ svG,
    int* __restrict__ C1G, int* __restrict__ C2G, int* __restrict__ flagG) {
  __shared__ int hist[NBIN];
  __shared__ unsigned long long keys[MAXC];
  __shared__ int wsum[16];
  __shared__ int Ts, cnts, ovf;
  int b = blockIdx.x, tid = threadIdx.x, ln = tid & 63, w = tid >> 6;
  const unsigned* v32 = v32G + b * NPROP;
  if (tid == 0) { Ts = NBIN - 1; cnts = 0; ovf = 0; }
  for (int i = tid; i < NBIN; i += 1024) hist[i] = 0;
  __syncthreads();
  for (int p = tid; p < NPROP; p += 1024) {
    unsigned v = v32[p];
    if (v != 0xFFFFFFFFu) atomicAdd(&hist[v >> 20], 1);
  }
  __syncthreads();
  {  // shuffle-scan 4096 bins -> threshold bin Ts (cum >= SEL), total valid
    int t = tid;
    int b0 = hist[4*t], b1 = hist[4*t+1], b2 = hist[4*t+2], b3 = hist[4*t+3];
    int s1 = b0 + b1, s2 = s1 + b2, s3 = s2 + b3;
    int v = s3;
#pragma unroll
    for (int o = 1; o < 64; o <<= 1) { int n = __shfl_up(v, o); if (ln >= o) v += n; }
    if (ln == 63) wsum[w] = v;
    __syncthreads();
    if (t < 16) {
      int x = wsum[t];
#pragma unroll
      for (int o = 1; o < 16; o <<= 1) { int n = __shfl_up(x, o); if (t >= o) x += n; }
      wsum[t] = x;
    }
    __syncthreads();
    int incl = ((w > 0) ? wsum[w - 1] : 0) + v;
    int off = incl - s3;
    int c0 = off + b0, c1 = off + s1, c2 = off + s2, c3 = off + s3;
    if      (c0 >= SEL && off < SEL) Ts = 4*t;
    else if (c1 >= SEL && c0  < SEL) Ts = 4*t+1;
    else if (c2 >= SEL && c1  < SEL) Ts = 4*t+2;
    else if (c3 >= SEL && c2  < SEL) Ts = 4*t+3;
  }
  __syncthreads();
  int T = Ts, nvTot = wsum[15];
  // compact tranche-1 (bin <= T) into LDS keys
  for (int p = tid; p < NPROP; p += 1024) {
    unsigned v = v32[p];
    bool cand = (v != 0xFFFFFFFFu) && ((int)(v >> 20) <= T);
    unsigned long long mb = __ballot(cand);
    int lpos = (int)__popcll(mb & ((1ull << ln) - 1ull));
    int wb = 0;
    if (ln == 0 && mb) wb = atomicAdd(&cnts, (int)__popcll(mb));
    wb = __shfl(wb, 0);
    if (cand) {
      int dst = wb + lpos;
      if (dst < MAXC) keys[dst] = ((unsigned long long)v << 16) | (unsigned)p;
      else ovf = 1;
    }
  }
  __syncthreads();
  int C1 = cnts;
  if (C1 > MAXC || ovf) {   // fat-bin overflow -> exact fallback path
    if (tid == 0) { flagG[b] = 1; C1G[b] = 0; C2G[b] = nvTot; }
    return;
  }
  // rank-sort: only threads < C1 participate (~6 waves issue the LDS loop)
  if (tid < C1) {
    unsigned long long myk = keys[tid];
    int rank = 0;
#pragma unroll 4
    for (int j = 0; j < C1; ++j) rank += (keys[j] < myk) ? 1 : 0;
    srowG[b * MAXC + rank] = (unsigned short)(myk & 0xFFFFull);
    svG[b * MAXC + rank]   = (unsigned)(myk >> 16);
  }
  if (tid == 0) { flagG[b] = 0; C1G[b] = C1; C2G[b] = nvTot; }
}

// ---------------------------------------------------------------------------
// K3 (wide, 72x256): zero all output + decode the selected boxes to global.
// Scattered reg gathers run at high CU parallelism here, not on 4 CUs.
// ---------------------------------------------------------------------------
__global__ __launch_bounds__(256) void prep_kernel(
    const float* __restrict__ reg, const float* __restrict__ lp,
    const float* __restrict__ rp, const unsigned short* __restrict__ ci16G,
    const unsigned short* __restrict__ srowG, const int* __restrict__ C1G,
    const int* __restrict__ flagG, float* __restrict__ out,
    float4* __restrict__ bxLG, float4* __restrict__ bxRG,
    float* __restrict__ arLG, float* __restrict__ arRG) {
  int g = blockIdx.x * 256 + threadIdx.x;       // 0..18431
  float4 z4 = make_float4(0.f, 0.f, 0.f, 0.f);
  ((float4*)out)[g] = z4;                       // 4*2048*9/4 = 18432 exactly
  if (g < NIMG * MAXC) {
    int b = g / MAXC, pos = g - b * MAXC;
    float4 L = z4, R = z4; float al = 1.0f, ar = 1.0f;
    if (flagG[b] == 0 && pos < C1G[b]) {
      int row  = srowG[b * MAXC + pos];
      int grow = b * NPROP + row;
      int ci   = ci16G[grow];
      L = decode_side(reg, (const float4*)lp, grow, ci, 0);
      R = decode_side(reg, (const float4*)rp, grow, ci, 1);
      al = areaf(L); ar = areaf(R);
    }
    bxLG[g] = L; bxRG[g] = R; arLG[g] = al; arRG[g] = ar;
  }
}

// ---------------------------------------------------------------------------
// K4: per image: all-LDS chunked dual greedy NMS over sorted tranche-1,
// early stop at 100 AND-survivors, direct output. Sets flag if exhausted
// with <100 survivors while more candidates exist (-> K5 redoes exactly).
// ---------------------------------------------------------------------------
struct SK {
  float4 bxL[MAXC], bxR[MAXC];           // 20 KB
  float  arL[MAXC], arR[MAXC];           // 5 KB
  unsigned short srow[MAXC];             // 1.25 KB
  unsigned sv[MAXC];                     // 2.5 KB
  unsigned long long keepbL[MAXC/64], keepbR[MAXC/64];
  unsigned long long rowmL[64], rowmR[64];
  float4 cbL[64], cbR[64];
  float  cbLa[64], cbRa[64];
  unsigned long long aL, aR;
  int prevCount, done, ccL, ccR, flag_s, C1_s, C2_s;
  unsigned kthV;
};                                        // ~33 KB

__global__ __launch_bounds__(1024) void nmsfast_kernel(
    const float4* __restrict__ bxLG, const float4* __restrict__ bxRG,
    const float* __restrict__ arLG, const float* __restrict__ arRG,
    const unsigned short* __restrict__ srowG, const unsigned* __restrict__ svG,
    const int* __restrict__ C1G, const int* __restrict__ C2G,
    int* __restrict__ flagG, float* __restrict__ out) {
  __shared__ SK S;
  int b = blockIdx.x, tid = threadIdx.x, ln = tid & 63, w = tid >> 6;
  float* ob = out + (size_t)b * NPROP * 9;
  if (tid == 0) {
    S.flag_s = flagG[b]; S.C1_s = C1G[b]; S.C2_s = C2G[b];
    S.prevCount = 0; S.done = 0; S.kthV = 0u;
  }
  __syncthreads();
  if (S.flag_s) return;                   // K5 handles this image
  int C1 = S.C1_s, C2t = S.C2_s;
  int CbEnd = (C1 + 63) & ~63;
  for (int i = tid; i < CbEnd; i += 1024) {   // coalesced LDS staging
    S.bxL[i] = bxLG[b * MAXC + i]; S.bxR[i] = bxRG[b * MAXC + i];
    S.arL[i] = arLG[b * MAXC + i]; S.arR[i] = arRG[b * MAXC + i];
    if (i < C1) { S.srow[i] = srowG[b * MAXC + i]; S.sv[i] = svG[b * MAXC + i]; }
    else        { S.srow[i] = 0;                   S.sv[i] = 0xFFFFFFFFu; }
  }
  for (int wd = tid; wd < (CbEnd >> 6); wd += 1024) {
    int b0 = wd << 6;
    unsigned long long mf = 0ull;
    if (C1 >= b0 + 64) mf = ~0ull;
    else if (C1 > b0)  mf = (1ull << (C1 - b0)) - 1ull;
    S.keepbL[wd] = mf; S.keepbR[wd] = mf;
  }
  __syncthreads();

  for (int base = 0; base < CbEnd; base += 64) {
    // ph1: 64x64 IoU bit matrices; waves 0-7 L, 8-15 R; rows via shfl
    {
      int isR = (w >= 8);
      float4 cbx = isR ? S.bxR[base + ln] : S.bxL[base + ln];
      float  car = isR ? S.arR[base + ln] : S.arL[base + ln];
      int w8 = w & 7;
#pragma unroll
      for (int k = 0; k < 8; ++k) {
        int row = w8 * 8 + k;
        float4 rbx;
        rbx.x = __shfl(cbx.x, row); rbx.y = __shfl(cbx.y, row);
        rbx.z = __shfl(cbx.z, row); rbx.w = __shfl(cbx.w, row);
        float rar = __shfl(car, row);
        bool bit = (ln > row) && iou_gt(rbx, rar, cbx, car);
        unsigned long long bal = __ballot(bit);
        if (ln == 0) { if (isR) S.rowmR[row] = bal; else S.rowmL[row] = bal; }
      }
    }
    __syncthreads();
    // ph2: branchless serial greedy per side (waves 0=L, 1=R)
    if (tid < 128) {
      int isR = (tid >= 64);
      unsigned long long* km = isR ? S.keepbR : S.keepbL;
      unsigned long long* rm = isR ? S.rowmR  : S.rowmL;
      unsigned long long a = km[base >> 6];
#pragma unroll
      for (int j = 0; j < 64; ++j)
        a &= ~((0ull - ((a >> j) & 1ull)) & rm[j]);
      if (ln == 0) {
        km[base >> 6] = a;
        if (isR) { S.aR = a; S.ccR = __popcll(a); }
        else     { S.aL = a; S.ccL = __popcll(a); }
      }
      if ((a >> ln) & 1ull) {
        int pos = __popcll(a & ((1ull << ln) - 1ull));
        if (isR) { S.cbR[pos] = S.bxR[base + ln]; S.cbRa[pos] = S.arR[base + ln]; }
        else     { S.cbL[pos] = S.bxL[base + ln]; S.cbLa[pos] = S.arL[base + ln]; }
      }
    }
    __syncthreads();
    // ph2b (wave 0): AND-survivors -> rank, kth, output, stop check
    if (w == 0) {
      unsigned long long m = S.aL & S.aR;
      int before = S.prevCount;
      bool bit = (m >> ln) & 1ull;
      int rank = before + (int)__popcll(m & ((1ull << ln) - 1ull));
      unsigned vA = S.sv[base + ln];
      unsigned long long selm = __ballot(bit && rank == DETS - 1);
      unsigned keffV = S.kthV;
      if (selm) keffV = __shfl(vA, __ffsll(selm) - 1);
      bool qual = bit && (rank < DETS || vA == keffV);
      if (qual) {
        int row = S.srow[base + ln];
        float4 L = S.bxL[base + ln], R = S.bxR[base + ln];
        float s = score_from_v(vA);
        float* orow = ob + row * 9;
        orow[0]=L.x; orow[1]=L.y; orow[2]=L.z; orow[3]=L.w;
        orow[4]=R.x; orow[5]=R.y; orow[6]=R.z; orow[7]=R.w;
        orow[8]=s;
      }
      if (ln == 0) {
        if (selm) S.kthV = keffV;
        int nc = before + (int)__popcll(m);
        S.prevCount = nc;
        if (nc >= DETS) {
          int nxt = base + 64;
          bool cont = (nxt < C1) && (S.sv[nxt] == keffV);
          if (!cont) S.done = 1;
        }
      }
    } else {
      // ph3 (waves 1-15): chunk survivors suppress later alive positions
      int cL = S.ccL, cR = S.ccR;
      if ((cL | cR) != 0) {
        for (int p = base + 64 + (tid - 64); p < CbEnd; p += 960) {
          bool aliveL = (S.keepbL[p >> 6] >> (p & 63)) & 1ull;
          bool aliveR = (S.keepbR[p >> 6] >> (p & 63)) & 1ull;
          if (!aliveL && !aliveR) continue;
          float4 mbL = S.bxL[p]; float al = S.arL[p];
          if (aliveL) {
            bool supL = false;
            for (int q = 0; q < cL; ++q)
              supL = supL || iou_gt(mbL, al, S.cbL[q], S.cbLa[q]);
            if (supL) atomicAnd(&S.keepbL[p >> 6], ~(1ull << (p & 63)));
          }
          float4 mbR = S.bxR[p]; float ar_ = S.arR[p];
          if (aliveR) {
            bool supR = false;
            for (int q = 0; q < cR; ++q)
              supR = supR || iou_gt(mbR, ar_, S.cbR[q], S.cbRa[q]);
            if (supR) atomicAnd(&S.keepbR[p >> 6], ~(1ull << (p & 63)));
          }
        }
      }
    }
    __syncthreads();
    if (S.done) break;
  }
  if (tid == 0 && S.prevCount < DETS && C2t > C1) flagG[b] = 1;
}

// ---------------------------------------------------------------------------
// K5: dormant exact fallback (R6's verified full-scope kernel, flag-gated).
// ---------------------------------------------------------------------------
struct SN {
  unsigned long long keys[NPROP];
  unsigned short sidx[NPROP];
  unsigned v32s[NPROP];
  float4 bxL[MAXC], bxR[MAXC];
  float  arL[MAXC], arR[MAXC];
  unsigned long long keepbL[NPROP / 64], keepbR[NPROP / 64];
  unsigned long long rowmL[64], rowmR[64];
  float4 cbL[64], cbR[64];
  float  cbLa[64], cbRa[64];
  unsigned long long aL, aR;
  int cnt, prevCount, done, ccL, ccR, flag_s;
  unsigned kthV;
};

__device__ __forceinline__ float4 get_sboxN(SN* S, const float* reg,
                                            const float4* lp4, const float4* rp4,
                                            const unsigned short* ci16G,
                                            int b, int pos, int isR) {
  if (pos < MAXC) return isR ? S->bxR[pos] : S->bxL[pos];
  int row = S->sidx[pos];
  int grow = b * NPROP + row;
  return decode_side(reg, isR ? rp4 : lp4, grow, ci16G[grow], isR);
}

__global__ __launch_bounds__(1024) void fallback_kernel(
    const float* __restrict__ reg, const float* __restrict__ lp,
    const float* __restrict__ rp, const unsigned* __restrict__ v32G,
    const unsigned short* __restrict__ ci16G, const int* __restrict__ flagG,
    float* __restrict__ out) {
  __shared__ SN S;
  int b = blockIdx.x, tid = threadIdx.x, ln = tid & 63, w = tid >> 6;
  if (tid == 0) { S.flag_s = flagG[b]; S.cnt = 0; S.prevCount = 0; S.done = 0; S.kthV = 0u; }
  __syncthreads();
  if (!S.flag_s) return;
  const float4* lp4 = (const float4*)lp;
  const float4* rp4 = (const float4*)rp;
  float* ob = out + (size_t)b * NPROP * 9;
  float4* ob4 = (float4*)ob;
  float4 z4 = make_float4(0.f, 0.f, 0.f, 0.f);
  for (int i = tid; i < NPROP * 9 / 4; i += 1024) ob4[i] = z4;
  for (int p = tid; p < NPROP; p += 1024) {
    unsigned v = v32G[b * NPROP + p];
    S.v32s[p] = v;
    bool cand = (v != 0xFFFFFFFFu);
    unsigned long long mb = __ballot(cand);
    int lpos = (int)__popcll(mb & ((1ull << ln) - 1ull));
    int wb = 0;
    if (ln == 0 && mb) wb = atomicAdd(&S.cnt, (int)__popcll(mb));
    wb = __shfl(wb, 0);
    if (cand) S.keys[wb + lpos] = ((unsigned long long)v << 16) | (unsigned)p;
  }
  __syncthreads();
  int C2 = S.cnt;
  int CbEnd = (C2 + 63) & ~63;
  {
    int i0 = tid, i1 = tid + 1024;
    unsigned long long k0 = (i0 < C2) ? S.keys[i0] : ~0ull;
    unsigned long long k1 = (i1 < C2) ? S.keys[i1] : ~0ull;
    int r0 = 0, r1 = 0;
#pragma unroll 4
    for (int j = 0; j < C2; ++j) {
      unsigned long long kj = S.keys[j];
      r0 += (kj < k0) ? 1 : 0;
      r1 += (kj < k1) ? 1 : 0;
    }
    if (i0 < C2) S.sidx[r0] = (unsigned short)(k0 & 0xFFFFull);
    if (i1 < C2) S.sidx[r1] = (unsigned short)(k1 & 0xFFFFull);
  }
  for (int i = C2 + tid; i < CbEnd; i += 1024) S.sidx[i] = 0;
  for (int wd = tid; wd < NPROP / 64; wd += 1024) {
    int b0 = wd << 6;
    unsigned long long mf = 0ull;
    if (C2 >= b0 + 64) mf = ~0ull;
    else if (C2 > b0)  mf = (1ull << (C2 - b0)) - 1ull;
    S.keepbL[wd] = mf; S.keepbR[wd] = mf;
  }
  __syncthreads();
  {
    int lim = min(CbEnd, MAXC);
    for (int i = tid; i < lim; i += 1024) {
      if (i < C2) {
        int row = S.sidx[i];
        int grow = b * NPROP + row;
        int ci = ci16G[grow];
        float4 L = decode_side(reg, lp4, grow, ci, 0);
        float4 R = decode_side(reg, rp4, grow, ci, 1);
        S.bxL[i] = L; S.arL[i] = areaf(L);
        S.bxR[i] = R; S.arR[i] = areaf(R);
      } else {
        S.bxL[i] = z4; S.arL[i] = 1.0f;
        S.bxR[i] = z4; S.arR[i] = 1.0f;
      }
    }
  }
  __syncthreads();
  for (int base = 0; base < CbEnd; base += 64) {
    {
      int isR = (w >= 8);
      float4 cbx = get_sboxN(&S, reg, lp4, rp4, ci16G, b, base + ln, isR);
      float car = (base + ln < MAXC) ? (isR ? S.arR[base + ln] : S.arL[base + ln])
                                     : areaf(cbx);
      int w8 = w & 7;
#pragma unroll
      for (int k = 0; k < 8; ++k) {
        int row = w8 * 8 + k;
        float4 rbx;
        rbx.x = __shfl(cbx.x, row); rbx.y = __shfl(cbx.y, row);
        rbx.z = __shfl(cbx.z, row); rbx.w = __shfl(cbx.w, row);
        float rar = __shfl(car, row);
        bool bit = (ln > row) && iou_gt(rbx, rar, cbx, car);
        unsigned long long bal = __ballot(bit);
        if (ln == 0) { if (isR) S.rowmR[row] = bal; else S.rowmL[row] = bal; }
      }
    }
    __syncthreads();
    if (tid < 128) {
      int isR = (tid >= 64);
      unsigned long long* km = isR ? S.keepbR : S.keepbL;
      unsigned long long* rm = isR ? S.rowmR  : S.rowmL;
      unsigned long long a = km[base >> 6];
#pragma unroll
      for (int j = 0; j < 64; ++j)
        a &= ~((0ull - ((a >> j) & 1ull)) & rm[j]);
      if (ln == 0) {
        km[base >> 6] = a;
        if (isR) { S.aR = a; S.ccR = __popcll(a); }
        else     { S.aL = a; S.ccL = __popcll(a); }
      }
      if ((a >> ln) & 1ull) {
        int pos = __popcll(a & ((1ull << ln) - 1ull));
        float4 v = get_sboxN(&S, reg, lp4, rp4, ci16G, b, base + ln, isR);
        if (isR) { S.cbR[pos] = v; S.cbRa[pos] = areaf(v); }
        else     { S.cbL[pos] = v; S.cbLa[pos] = areaf(v); }
      }
    }
    __syncthreads();
    if (w == 0) {
      unsigned long long m = S.aL & S.aR;
      int before = S.prevCount;
      bool bit = (m >> ln) & 1ull;
      int rank = before + (int)__popcll(m & ((1ull << ln) - 1ull));
      int row = S.sidx[base + ln];
      unsigned vA = S.v32s[row];
      unsigned long long selm = __ballot(bit && rank == DETS - 1);
      unsigned keffV = S.kthV;
      if (selm) keffV = __shfl(vA, __ffsll(selm) - 1);
      bool qual = bit && (rank < DETS || vA == keffV);
      if (qual) {
        float4 L = get_sboxN(&S, reg, lp4, rp4, ci16G, b, base + ln, 0);
        float4 R = get_sboxN(&S, reg, lp4, rp4, ci16G, b, base + ln, 1);
        float s = score_from_v(vA);
        float* orow = ob + row * 9;
        orow[0]=L.x; orow[1]=L.y; orow[2]=L.z; orow[3]=L.w;
        orow[4]=R.x; orow[5]=R.y; orow[6]=R.z; orow[7]=R.w;
        orow[8]=s;
      }
      if (ln == 0) {
        if (selm) S.kthV = keffV;
        int nc = before + (int)__popcll(m);
        S.prevCount = nc;
        if (nc >= DETS) {
          int nxt = base + 64;
          bool cont = false;
          if (nxt < C2) cont = (S.v32s[S.sidx[nxt]] == keffV);
          if (!cont) S.done = 1;
        }
      }
    } else {
      int cL = S.ccL, cR = S.ccR;
      if ((cL | cR) != 0) {
        for (int p = base + 64 + (tid - 64); p < CbEnd; p += 960) {
          float4 mbL = get_sboxN(&S, reg, lp4, rp4, ci16G, b, p, 0);
          float al = (p < MAXC) ? S.arL[p] : areaf(mbL);
          bool supL = false;
          for (int q = 0; q < cL; ++q)
            supL = supL || iou_gt(mbL, al, S.cbL[q], S.cbLa[q]);
          if (supL) atomicAnd(&S.keepbL[p >> 6], ~(1ull << (p & 63)));
          float4 mbR = get_sboxN(&S, reg, lp4, rp4, ci16G, b, p, 1);
          float ar_ = (p < MAXC) ? S.arR[p] : areaf(mbR);
          bool supR = false;
          for (int q = 0; q < cR; ++q)
            supR = supR || iou_gt(mbR, ar_, S.cbR[q], S.cbRa[q]);
          if (supR) atomicAnd(&S.keepbR[p >> 6], ~(1ull << (p & 63)));
        }
      }
    }
    __syncthreads();
    if (S.done) break;
  }
}

// ---------------------------------------------------------------------------
extern "C" void kernel_launch(void* const* d_in, const int* in_sizes, int n_in,
                              void* d_out, int out_size, void* d_ws, size_t ws_size,
                              hipStream_t stream) {
  const float* logits = (const float*)d_in[0];   // [8192, 81]
  const float* reg    = (const float*)d_in[1];   // [8192, 648]
  const float* lprop  = (const float*)d_in[2];   // [8192, 4]
  const float* rprop  = (const float*)d_in[3];   // [8192, 4]
  float* out = (float*)d_out;                    // [4, 2048, 9]

  char* ws = (char*)d_ws;                        // ~167 KB used
  unsigned*       v32G  = (unsigned*)(ws + 0);
  unsigned short* ci16G = (unsigned short*)(ws + 32768);
  unsigned short* srowG = (unsigned short*)(ws + 49152);
  unsigned*       svG   = (unsigned*)(ws + 54272);
  float4*         bxLG  = (float4*)(ws + 64512);
  float4*         bxRG  = (float4*)(ws + 105472);
  float*          arLG  = (float*)(ws + 146432);
  float*          arRG  = (float*)(ws + 156672);
  int*            C1G   = (int*)(ws + 166912);
  int*            C2G   = (int*)(ws + 166928);
  int*            flagG = (int*)(ws + 166944);

  score_kernel   <<<NIMG * NPROP / 4, 256,  0, stream>>>(logits, v32G, ci16G);
  select_kernel  <<<NIMG,             1024, 0, stream>>>(v32G, srowG, svG, C1G, C2G, flagG);
  prep_kernel    <<<72,               256,  0, stream>>>(reg, lprop, rprop, ci16G, srowG,
                                                         C1G, flagG, out, bxLG, bxRG, arLG, arRG);
  nmsfast_kernel <<<NIMG,             1024, 0, stream>>>(bxLG, bxRG, arLG, arRG, srowG, svG,
                                                         C1G, C2G, flagG, out);
  fallback_kernel<<<NIMG,             1024, 0, stream>>>(reg, lprop, rprop, v32G, ci16G,
                                                         flagG, out);
}